// Round 6
// baseline (136.610 us; speedup 1.0000x reference)
//
#include <hip/hip_runtime.h>

// Problem constants
#define NB   4096   // B
#define ND   256    // D
#define N2B  8192   // 2B
#define INV_T 2.0f  // 1/TEMP
#define C_EXP 2.8853900817779268f  // 2*log2(e): exp(s*2) == exp2(s*C_EXP)

typedef __attribute__((ext_vector_type(8))) short bf16x8;
typedef __attribute__((ext_vector_type(16))) float f32x16;

// fp32 -> bf16 (RNE) as raw bits
__device__ __forceinline__ unsigned short f2b(float f) {
  unsigned int u = __float_as_uint(f);
  u = (u + 0x7fffu + ((u >> 16) & 1u)) >> 16;
  return (unsigned short)u;
}
__device__ __forceinline__ float b2f(unsigned short h) {
  return __uint_as_float(((unsigned int)h) << 16);
}

// Kernel A: L2-normalize rows of [x_i; x_j] -> Z (bf16) and Zs (bf16,
// pre-scaled by C_EXP so the GEMM epilogue is a bare exp2).
//   diagE[zrow] = exp(diag/T)   (self term, subtracted in k_final)
//   pos[r] = dot(z_i[r], z_j[r]) (LDS exchange between i- and j-waves)
// Block 0 zero-inits lossAcc and ticket.
__global__ __launch_bounds__(256) void k_normalize(
    const float* __restrict__ xi, const float* __restrict__ xj,
    unsigned short* __restrict__ Z, unsigned short* __restrict__ Zs,
    float* __restrict__ diagE, float* __restrict__ pos,
    float* __restrict__ lossAcc, unsigned int* __restrict__ ticket) {
  __shared__ float sh[2][256];
  if (blockIdx.x == 0 && threadIdx.x == 0) { *lossAcc = 0.0f; *ticket = 0u; }
  int wave = threadIdx.x >> 6, lane = threadIdx.x & 63;
  int r = (int)blockIdx.x * 2 + (wave & 1);  // row in [0, NB)
  bool isJ = wave >= 2;
  const float* src = (isJ ? xj : xi) + (size_t)r * ND;
  int zrow = r + (isJ ? NB : 0);

  float4 v = *(const float4*)(src + lane * 4);
  float ss = v.x * v.x + v.y * v.y + v.z * v.z + v.w * v.w;
#pragma unroll
  for (int m = 1; m < 64; m <<= 1) ss += __shfl_xor(ss, m, 64);
  float scale = 1.0f / fmaxf(sqrtf(ss), 1e-12f);
  unsigned short h0 = f2b(v.x * scale), h1 = f2b(v.y * scale);
  unsigned short h2 = f2b(v.z * scale), h3 = f2b(v.w * scale);
  ushort4 st; st.x = h0; st.y = h1; st.z = h2; st.w = h3;
  *(ushort4*)(Z + (size_t)zrow * ND + lane * 4) = st;

  float f0 = b2f(h0), f1 = b2f(h1), f2 = b2f(h2), f3 = b2f(h3);
  ushort4 sts;
  sts.x = f2b(f0 * C_EXP); sts.y = f2b(f1 * C_EXP);
  sts.z = f2b(f2 * C_EXP); sts.w = f2b(f3 * C_EXP);
  *(ushort4*)(Zs + (size_t)zrow * ND + lane * 4) = sts;

  float d = f0 * f0 + f1 * f1 + f2 * f2 + f3 * f3;
#pragma unroll
  for (int m = 1; m < 64; m <<= 1) d += __shfl_xor(d, m, 64);
  if (lane == 0) diagE[zrow] = __expf(d * INV_T);

  if (isJ) {
    float* s = sh[wave & 1] + lane * 4;
    s[0] = f0; s[1] = f1; s[2] = f2; s[3] = f3;
  }
  __syncthreads();
  if (!isJ) {
    const float* s = sh[wave] + lane * 4;
    float p = f0 * s[0] + f1 * s[1] + f2 * s[2] + f3 * s[3];
#pragma unroll
    for (int m = 1; m < 64; m <<= 1) p += __shfl_xor(p, m, 64);
    if (lane == 0) pos[r] = p;
  }
}

// Kernel B: A-stationary, NO-LDS, NO-BARRIER band GEMM + fused exp2/rowsum.
// Grid 512 = 32 row-bands (256 rows) x 16 col-spans (512 cols).
// Wave owns 64 A-rows (Zs, pre-scaled) in registers; B fragments load
// DIRECTLY from Z via L2 (Z = 4 MB; per-XCD resident B-span ~512 KB).
// 16 col-groups of 32 cols; per group: 16 bf16x8 B-loads, 32 chained
// 32x32x16 MFMAs (2 row-groups), exp2-accumulate into rs. Zero sync points:
// waves free-run, compiler pipelines loads across groups, 2 waves/SIMD
// co-schedule MFMA against VALU. Rowsum partials -> R[row][16], no atomics.
__global__ __launch_bounds__(256, 2) void k_gemm_exp(
    const unsigned short* __restrict__ Zs, const unsigned short* __restrict__ Z,
    float* __restrict__ R) {
  int tid = threadIdx.x;
  int wave = tid >> 6, lane = tid & 63;
  int r5 = lane & 31, h = lane >> 5;
  int band = (int)blockIdx.x >> 4;   // 0..31
  int span = (int)blockIdx.x & 15;   // 0..15
  int rowA = band * 256 + wave * 64;

  // A fragments (pre-scaled): layout A[m=r5][k=h*8+j], 16 K-steps.
  bf16x8 afr[2][16];
#pragma unroll
  for (int rg = 0; rg < 2; ++rg)
#pragma unroll
    for (int kk = 0; kk < 16; ++kk)
      afr[rg][kk] = *(const bf16x8*)(Zs + (size_t)(rowA + rg * 32 + r5) * ND +
                                     kk * 16 + h * 8);

  float rs[2][16];
#pragma unroll
  for (int rg = 0; rg < 2; ++rg)
#pragma unroll
    for (int g = 0; g < 16; ++g) rs[rg][g] = 0.0f;

  // B base: lane r5 reads Z-row (span*512 + g*32 + r5), 16B at k-offset
  // kk*32B + h*16B. Layout B[n=r5][k=h*8+j].
  const unsigned short* bbase = Z + (size_t)(span * 512 + r5) * ND + h * 8;

  for (int g = 0; g < 16; ++g) {
    const unsigned short* bp = bbase + (size_t)g * 32 * ND;
    f32x16 acc0 = {};
    f32x16 acc1 = {};
#pragma unroll
    for (int kk = 0; kk < 16; ++kk) {
      bf16x8 bf = *(const bf16x8*)(bp + kk * 16);
      acc0 = __builtin_amdgcn_mfma_f32_32x32x16_bf16(afr[0][kk], bf, acc0, 0,
                                                     0, 0);
      acc1 = __builtin_amdgcn_mfma_f32_32x32x16_bf16(afr[1][kk], bf, acc1, 0,
                                                     0, 0);
    }
#pragma unroll
    for (int q = 0; q < 16; ++q) {
      rs[0][q] += exp2f(acc0[q]);
      rs[1][q] += exp2f(acc1[q]);
    }
  }

  // Reduce across the 32 col-lanes (C/D col = lane&31): masks 1..16.
#pragma unroll
  for (int m = 1; m <= 16; m <<= 1)
#pragma unroll
    for (int rg = 0; rg < 2; ++rg)
#pragma unroll
      for (int g = 0; g < 16; ++g)
        rs[rg][g] += __shfl_xor(rs[rg][g], m, 64);

  // C/D row = (reg&3) + 8*(reg>>2) + 4*h (+ rg*32). Writer: r5 == reg.
#pragma unroll
  for (int rg = 0; rg < 2; ++rg)
#pragma unroll
    for (int g = 0; g < 16; ++g)
      if (r5 == g) {
        int rowIn = (g & 3) + 8 * (g >> 2) + 4 * h;
        R[(size_t)(rowA + rg * 32 + rowIn) * 16 + span] = rs[rg][g];
      }
}

// Kernel C: 32 blocks x 256 rows. rowsum[r] = sum_{q<16} R[r][q] - diagE[r];
// term = log(rowsum) - pos[r%B]/T. Block-reduce -> one atomicAdd per block;
// ticketed last block writes out = lossAcc / 2B.
__global__ __launch_bounds__(256) void k_final(
    const float* __restrict__ R, const float* __restrict__ diagE,
    const float* __restrict__ pos, float* __restrict__ lossAcc,
    unsigned int* __restrict__ ticket, float* __restrict__ out) {
  __shared__ float red[4];
  int tid = threadIdx.x;
  int wave = tid >> 6, lane = tid & 63;
  int row = (int)blockIdx.x * 256 + tid;

  const float* Rr = R + (size_t)row * 16;
  float s = -diagE[row];
#pragma unroll
  for (int i = 0; i < 4; ++i) {
    float4 a = *(const float4*)(Rr + i * 4);
    s += (a.x + a.y) + (a.z + a.w);
  }
  float term = __logf(s) - INV_T * pos[row & (NB - 1)];
#pragma unroll
  for (int m = 1; m < 64; m <<= 1) term += __shfl_xor(term, m, 64);
  if (lane == 0) red[wave] = term;
  __syncthreads();
  if (tid == 0) {
    float bs = red[0] + red[1] + red[2] + red[3];
    atomicAdd(lossAcc, bs);
    __threadfence();
    unsigned int old = atomicAdd(ticket, 1u);
    if (old == 31u) {
      float v = atomicAdd(lossAcc, 0.0f);  // atomic read after all adds
      out[0] = v * (1.0f / (float)N2B);
    }
  }
}

extern "C" void kernel_launch(void* const* d_in, const int* in_sizes, int n_in,
                              void* d_out, int out_size, void* d_ws,
                              size_t ws_size, hipStream_t stream) {
  const float* xi = (const float*)d_in[0];
  const float* xj = (const float*)d_in[1];
  float* out = (float*)d_out;
  char* ws = (char*)d_ws;
  unsigned short* Z = (unsigned short*)ws;            // 4 MiB (B operand)
  unsigned short* Zs = (unsigned short*)(ws + (4u << 20));  // 4 MiB (A, scaled)
  float* R = (float*)(ws + (8u << 20));               // 8192*16*4 = 512 KiB
  float* pos = (float*)(ws + (9u << 20));             // 16 KiB
  float* diagE = (float*)(ws + (9u << 20) + 65536);   // 32 KiB
  float* lossAcc = (float*)(ws + (9u << 20) + 131072);
  unsigned int* ticket = (unsigned int*)(ws + (9u << 20) + 131072 + 64);

  k_normalize<<<dim3(NB / 2), dim3(256), 0, stream>>>(xi, xj, Z, Zs, diagE,
                                                      pos, lossAcc, ticket);
  k_gemm_exp<<<dim3(512), dim3(256), 0, stream>>>(Zs, Z, R);
  k_final<<<dim3(32), dim3(256), 0, stream>>>(R, diagE, pos, lossAcc, ticket,
                                              out);
}

// Round 7
// 135.296 us; speedup vs baseline: 1.0097x; 1.0097x over previous
//
#include <hip/hip_runtime.h>

// Problem constants
#define NB   4096   // B
#define ND   256    // D
#define N2B  8192   // 2B
#define INV_T 2.0f  // 1/TEMP
#define C_EXP 2.8853900817779268f  // 2*log2(e): exp(s*2) == exp2(s*C_EXP)

typedef __attribute__((ext_vector_type(8))) short bf16x8;
typedef __attribute__((ext_vector_type(16))) float f32x16;

__device__ __forceinline__ void gload_lds16(const void* g, void* l) {
  __builtin_amdgcn_global_load_lds(
      (const __attribute__((address_space(1))) void*)g,
      (__attribute__((address_space(3))) void*)l, 16, 0, 0);
}

// fp32 -> bf16 (RNE) as raw bits
__device__ __forceinline__ unsigned short f2b(float f) {
  unsigned int u = __float_as_uint(f);
  u = (u + 0x7fffu + ((u >> 16) & 1u)) >> 16;
  return (unsigned short)u;
}
__device__ __forceinline__ float b2f(unsigned short h) {
  return __uint_as_float(((unsigned int)h) << 16);
}

// Kernel A: L2-normalize rows of [x_i; x_j] -> Z (bf16) and Zs (bf16,
// pre-scaled by C_EXP so the GEMM epilogue is a bare exp2).
//   diagE[zrow] = exp(diag/T)   (self term, subtracted in k_final)
//   pos[r] = dot(z_i[r], z_j[r]) (LDS exchange between i- and j-waves)
// Block 0 zero-inits lossAcc and ticket.
__global__ __launch_bounds__(256) void k_normalize(
    const float* __restrict__ xi, const float* __restrict__ xj,
    unsigned short* __restrict__ Z, unsigned short* __restrict__ Zs,
    float* __restrict__ diagE, float* __restrict__ pos,
    float* __restrict__ lossAcc, unsigned int* __restrict__ ticket) {
  __shared__ float sh[2][256];
  if (blockIdx.x == 0 && threadIdx.x == 0) { *lossAcc = 0.0f; *ticket = 0u; }
  int wave = threadIdx.x >> 6, lane = threadIdx.x & 63;
  int r = (int)blockIdx.x * 2 + (wave & 1);  // row in [0, NB)
  bool isJ = wave >= 2;
  const float* src = (isJ ? xj : xi) + (size_t)r * ND;
  int zrow = r + (isJ ? NB : 0);

  float4 v = *(const float4*)(src + lane * 4);
  float ss = v.x * v.x + v.y * v.y + v.z * v.z + v.w * v.w;
#pragma unroll
  for (int m = 1; m < 64; m <<= 1) ss += __shfl_xor(ss, m, 64);
  float scale = 1.0f / fmaxf(sqrtf(ss), 1e-12f);
  unsigned short h0 = f2b(v.x * scale), h1 = f2b(v.y * scale);
  unsigned short h2 = f2b(v.z * scale), h3 = f2b(v.w * scale);
  ushort4 st; st.x = h0; st.y = h1; st.z = h2; st.w = h3;
  *(ushort4*)(Z + (size_t)zrow * ND + lane * 4) = st;

  float f0 = b2f(h0), f1 = b2f(h1), f2 = b2f(h2), f3 = b2f(h3);
  ushort4 sts;
  sts.x = f2b(f0 * C_EXP); sts.y = f2b(f1 * C_EXP);
  sts.z = f2b(f2 * C_EXP); sts.w = f2b(f3 * C_EXP);
  *(ushort4*)(Zs + (size_t)zrow * ND + lane * 4) = sts;

  float d = f0 * f0 + f1 * f1 + f2 * f2 + f3 * f3;
#pragma unroll
  for (int m = 1; m < 64; m <<= 1) d += __shfl_xor(d, m, 64);
  if (lane == 0) diagE[zrow] = __expf(d * INV_T);

  if (isJ) {
    float* s = sh[wave & 1] + lane * 4;
    s[0] = f0; s[1] = f1; s[2] = f2; s[3] = f3;
  }
  __syncthreads();
  if (!isJ) {
    const float* s = sh[wave] + lane * 4;
    float p = f0 * s[0] + f1 * s[1] + f2 * s[2] + f3 * s[3];
#pragma unroll
    for (int m = 1; m < 64; m <<= 1) p += __shfl_xor(p, m, 64);
    if (lane == 0) pos[r] = p;
  }
}

// Kernel B: A-stationary band GEMM with SINGLE-BARRIER structure.
// Grid 2048 = 32 row-bands (256 rows) x 64 col-spans (128 cols).
// Wave owns 64 A-rows (Zs, pre-scaled) in registers (128 VGPRs).
// The whole 128-col B-tile (64 KB) is staged into LDS ONCE via lds-dma
// (XOR-swizzled, conflict-free), then ONE barrier, then pure free-running
// compute: 4 col-groups x (16 ds_read_b128 + 32 chained 32x32x16 MFMAs +
// 32 exp2) per wave with ZERO further sync — the 2 waves/SIMD co-schedule
// MFMA against VALU/LDS. Rowsum partials -> R[row][64], no atomics.
#define SPAN 128
__global__ __launch_bounds__(256, 2) void k_gemm_exp(
    const unsigned short* __restrict__ Zs, const unsigned short* __restrict__ Z,
    float* __restrict__ R) {
  __shared__ alignas(16) unsigned short Bs[SPAN * ND];  // 64 KiB

  int tid = threadIdx.x;
  int wave = tid >> 6, lane = tid & 63;
  int r5 = lane & 31, h = lane >> 5;
  int band = (int)blockIdx.x & 31;   // 0..31
  int span = (int)blockIdx.x >> 5;   // 0..63
  int rowA = band * 256 + wave * 64;
  int col0 = span * SPAN;

  // Stage the full B-tile once: 16 dma calls/wave, 2 rows (1 KB) each.
  // LDS slot s of row zr holds global 16B-chunk (s ^ (zr&31)).
#pragma unroll
  for (int call = 0; call < 16; ++call) {
    int r0 = wave * 32 + call * 2;       // wave-uniform LDS base row
    int lrow = r0 + h;                   // LDS row this lane feeds
    int gc = r5 ^ (lrow & 31);           // source chunk for slot r5
    gload_lds16(Z + (size_t)(col0 + lrow) * ND + gc * 8, &Bs[r0 * ND]);
  }

  // A fragments (pre-scaled): layout A[m=r5][k=kk*16 + h*8 + j].
  bf16x8 afr[2][16];
#pragma unroll
  for (int rg = 0; rg < 2; ++rg)
#pragma unroll
    for (int kk = 0; kk < 16; ++kk)
      afr[rg][kk] = *(const bf16x8*)(Zs + (size_t)(rowA + rg * 32 + r5) * ND +
                                     kk * 16 + h * 8);

  float rs[2][16];
#pragma unroll
  for (int rg = 0; rg < 2; ++rg)
#pragma unroll
    for (int g = 0; g < 16; ++g) rs[rg][g] = 0.0f;

  asm volatile("s_waitcnt vmcnt(0)" ::: "memory");
  __syncthreads();  // the ONLY barrier

#pragma unroll
  for (int g = 0; g < 4; ++g) {
    f32x16 acc0 = {};
    f32x16 acc1 = {};
#pragma unroll
    for (int kk = 0; kk < 16; ++kk) {
      int row = g * 32 + r5;                 // B col (Z row) this lane holds
      int slot = (kk * 2 + h) ^ r5;          // logical chunk ^ (row&31)
      bf16x8 bf = *(const bf16x8*)&Bs[row * ND + slot * 8];
      acc0 = __builtin_amdgcn_mfma_f32_32x32x16_bf16(afr[0][kk], bf, acc0, 0,
                                                     0, 0);
      acc1 = __builtin_amdgcn_mfma_f32_32x32x16_bf16(afr[1][kk], bf, acc1, 0,
                                                     0, 0);
    }
#pragma unroll
    for (int q = 0; q < 16; ++q) {
      rs[0][q] += exp2f(acc0[q]);
      rs[1][q] += exp2f(acc1[q]);
    }
  }

  // Reduce across the 32 col-lanes (C/D col = lane&31): masks 1..16.
#pragma unroll
  for (int m = 1; m <= 16; m <<= 1)
#pragma unroll
    for (int rg = 0; rg < 2; ++rg)
#pragma unroll
      for (int g = 0; g < 16; ++g)
        rs[rg][g] += __shfl_xor(rs[rg][g], m, 64);

  // C/D row = (reg&3) + 8*(reg>>2) + 4*h (+ rg*32). Writer: r5 == reg.
#pragma unroll
  for (int rg = 0; rg < 2; ++rg)
#pragma unroll
    for (int g = 0; g < 16; ++g)
      if (r5 == g) {
        int rowIn = (g & 3) + 8 * (g >> 2) + 4 * h;
        R[(size_t)(rowA + rg * 32 + rowIn) * 64 + span] = rs[rg][g];
      }
}

// Kernel C: 32 blocks x 256 rows. rowsum[r] = sum_{q<64} R[r][q] - diagE[r];
// term = log(rowsum) - pos[r%B]/T. Block-reduce -> one atomicAdd per block;
// ticketed last block writes out = lossAcc / 2B.
__global__ __launch_bounds__(256) void k_final(
    const float* __restrict__ R, const float* __restrict__ diagE,
    const float* __restrict__ pos, float* __restrict__ lossAcc,
    unsigned int* __restrict__ ticket, float* __restrict__ out) {
  __shared__ float red[4];
  int tid = threadIdx.x;
  int wave = tid >> 6, lane = tid & 63;
  int row = (int)blockIdx.x * 256 + tid;

  const float* Rr = R + (size_t)row * 64;
  float s = -diagE[row];
#pragma unroll
  for (int i = 0; i < 16; ++i) {
    float4 a = *(const float4*)(Rr + i * 4);
    s += (a.x + a.y) + (a.z + a.w);
  }
  float term = __logf(s) - INV_T * pos[row & (NB - 1)];
#pragma unroll
  for (int m = 1; m < 64; m <<= 1) term += __shfl_xor(term, m, 64);
  if (lane == 0) red[wave] = term;
  __syncthreads();
  if (tid == 0) {
    float bs = red[0] + red[1] + red[2] + red[3];
    atomicAdd(lossAcc, bs);
    __threadfence();
    unsigned int old = atomicAdd(ticket, 1u);
    if (old == 31u) {
      float v = atomicAdd(lossAcc, 0.0f);  // atomic read after all adds
      out[0] = v * (1.0f / (float)N2B);
    }
  }
}

extern "C" void kernel_launch(void* const* d_in, const int* in_sizes, int n_in,
                              void* d_out, int out_size, void* d_ws,
                              size_t ws_size, hipStream_t stream) {
  const float* xi = (const float*)d_in[0];
  const float* xj = (const float*)d_in[1];
  float* out = (float*)d_out;
  char* ws = (char*)d_ws;
  unsigned short* Z = (unsigned short*)ws;                  // 4 MiB (B operand)
  unsigned short* Zs = (unsigned short*)(ws + (4u << 20));  // 4 MiB (A, scaled)
  float* R = (float*)(ws + (8u << 20));                     // 8192*64*4 = 2 MiB
  float* pos = (float*)(ws + (10u << 20));                  // 16 KiB
  float* diagE = (float*)(ws + (10u << 20) + 65536);        // 32 KiB
  float* lossAcc = (float*)(ws + (10u << 20) + 131072);
  unsigned int* ticket = (unsigned int*)(ws + (10u << 20) + 131072 + 64);

  k_normalize<<<dim3(NB / 2), dim3(256), 0, stream>>>(xi, xj, Z, Zs, diagE,
                                                      pos, lossAcc, ticket);
  k_gemm_exp<<<dim3(2048), dim3(256), 0, stream>>>(Zs, Z, R);
  k_final<<<dim3(32), dim3(256), 0, stream>>>(R, diagE, pos, lossAcc, ticket,
                                              out);
}

// Round 8
// 133.311 us; speedup vs baseline: 1.0248x; 1.0149x over previous
//
#include <hip/hip_runtime.h>

// Problem constants
#define NB   4096   // B
#define ND   256    // D
#define N2B  8192   // 2B
#define INV_T 2.0f  // 1/TEMP
#define C_EXP 2.8853900817779268f  // 2*log2(e): exp(s*2) == exp2(s*C_EXP)

typedef __attribute__((ext_vector_type(8))) short bf16x8;
typedef __attribute__((ext_vector_type(16))) float f32x16;

__device__ __forceinline__ void gload_lds16(const void* g, void* l) {
  __builtin_amdgcn_global_load_lds(
      (const __attribute__((address_space(1))) void*)g,
      (__attribute__((address_space(3))) void*)l, 16, 0, 0);
}

// fp32 -> bf16 (RNE) as raw bits
__device__ __forceinline__ unsigned short f2b(float f) {
  unsigned int u = __float_as_uint(f);
  u = (u + 0x7fffu + ((u >> 16) & 1u)) >> 16;
  return (unsigned short)u;
}
__device__ __forceinline__ float b2f(unsigned short h) {
  return __uint_as_float(((unsigned int)h) << 16);
}

// Kernel A: L2-normalize rows of [x_i; x_j] -> Z (bf16) and Zs (bf16,
// pre-scaled by C_EXP so the GEMM epilogue is a bare exp2).
//   diagE[zrow] = exp(diag/T)   (self term, subtracted in k_final)
//   pos[r] = dot(z_i[r], z_j[r]) (LDS exchange between i- and j-waves)
// Block 0 zero-inits lossAcc and ticket.
__global__ __launch_bounds__(256) void k_normalize(
    const float* __restrict__ xi, const float* __restrict__ xj,
    unsigned short* __restrict__ Z, unsigned short* __restrict__ Zs,
    float* __restrict__ diagE, float* __restrict__ pos,
    float* __restrict__ lossAcc, unsigned int* __restrict__ ticket) {
  __shared__ float sh[2][256];
  if (blockIdx.x == 0 && threadIdx.x == 0) { *lossAcc = 0.0f; *ticket = 0u; }
  int wave = threadIdx.x >> 6, lane = threadIdx.x & 63;
  int r = (int)blockIdx.x * 2 + (wave & 1);  // row in [0, NB)
  bool isJ = wave >= 2;
  const float* src = (isJ ? xj : xi) + (size_t)r * ND;
  int zrow = r + (isJ ? NB : 0);

  float4 v = *(const float4*)(src + lane * 4);
  float ss = v.x * v.x + v.y * v.y + v.z * v.z + v.w * v.w;
#pragma unroll
  for (int m = 1; m < 64; m <<= 1) ss += __shfl_xor(ss, m, 64);
  float scale = 1.0f / fmaxf(sqrtf(ss), 1e-12f);
  unsigned short h0 = f2b(v.x * scale), h1 = f2b(v.y * scale);
  unsigned short h2 = f2b(v.z * scale), h3 = f2b(v.w * scale);
  ushort4 st; st.x = h0; st.y = h1; st.z = h2; st.w = h3;
  *(ushort4*)(Z + (size_t)zrow * ND + lane * 4) = st;

  float f0 = b2f(h0), f1 = b2f(h1), f2 = b2f(h2), f3 = b2f(h3);
  ushort4 sts;
  sts.x = f2b(f0 * C_EXP); sts.y = f2b(f1 * C_EXP);
  sts.z = f2b(f2 * C_EXP); sts.w = f2b(f3 * C_EXP);
  *(ushort4*)(Zs + (size_t)zrow * ND + lane * 4) = sts;

  float d = f0 * f0 + f1 * f1 + f2 * f2 + f3 * f3;
#pragma unroll
  for (int m = 1; m < 64; m <<= 1) d += __shfl_xor(d, m, 64);
  if (lane == 0) diagE[zrow] = __expf(d * INV_T);

  if (isJ) {
    float* s = sh[wave & 1] + lane * 4;
    s[0] = f0; s[1] = f1; s[2] = f2; s[3] = f3;
  }
  __syncthreads();
  if (!isJ) {
    const float* s = sh[wave] + lane * 4;
    float p = f0 * s[0] + f1 * s[1] + f2 * s[2] + f3 * s[3];
#pragma unroll
    for (int m = 1; m < 64; m <<= 1) p += __shfl_xor(p, m, 64);
    if (lane == 0) pos[r] = p;
  }
}

// Kernel B: A-stationary band GEMM, single barrier, PINNED A registers.
// Grid 2048 = 32 row-bands (256 rows) x 64 col-spans (128 cols).
// Wave owns 64 A-rows (Zs, pre-scaled) in 128 PINNED VGPRs (opaque-asm
// pin prevents the compiler's rematerialization — R7's VGPR=116 proved it
// was reloading A from global inside the loop, serializing on L2 latency).
// B-tile (64 KB) staged to LDS once (lds-dma, XOR swizzle, conflict-free),
// one barrier, then free-running compute: 4 col-groups x (16 ds_read_b128 +
// 32 chained 32x32x16 MFMAs + 32 exp2). Partials -> R[row][64], no atomics.
#define SPAN 128
__global__ __launch_bounds__(256, 2) void k_gemm_exp(
    const unsigned short* __restrict__ Zs, const unsigned short* __restrict__ Z,
    float* __restrict__ R) {
  __shared__ alignas(16) unsigned short Bs[SPAN * ND];  // 64 KiB

  int tid = threadIdx.x;
  int wave = tid >> 6, lane = tid & 63;
  int r5 = lane & 31, h = lane >> 5;
  int band = (int)blockIdx.x & 31;   // 0..31
  int span = (int)blockIdx.x >> 5;   // 0..63
  int rowA = band * 256 + wave * 64;
  int col0 = span * SPAN;

  // A fragments first (their latency overlaps the staging dma below).
  // Layout A[m=r5][k=kk*16 + h*8 + j].
  bf16x8 afr[2][16];
#pragma unroll
  for (int rg = 0; rg < 2; ++rg)
#pragma unroll
    for (int kk = 0; kk < 16; ++kk)
      afr[rg][kk] = *(const bf16x8*)(Zs + (size_t)(rowA + rg * 32 + r5) * ND +
                                     kk * 16 + h * 8);

  // Stage the full B-tile once: 16 dma calls/wave, 2 rows (1 KB) each.
  // LDS slot s of row zr holds global 16B-chunk (s ^ (zr&31)).
#pragma unroll
  for (int call = 0; call < 16; ++call) {
    int r0 = wave * 32 + call * 2;       // wave-uniform LDS base row
    int lrow = r0 + h;                   // LDS row this lane feeds
    int gc = r5 ^ (lrow & 31);           // source chunk for slot r5
    gload_lds16(Z + (size_t)(col0 + lrow) * ND + gc * 8, &Bs[r0 * ND]);
  }

  float rs[2][16];
#pragma unroll
  for (int rg = 0; rg < 2; ++rg)
#pragma unroll
    for (int g = 0; g < 16; ++g) rs[rg][g] = 0.0f;

  asm volatile("s_waitcnt vmcnt(0)" ::: "memory");
  __syncthreads();  // the ONLY barrier

  // PIN: opaque asm makes afr values non-rematerializable — they must
  // stay resident in VGPRs for the whole compute loop.
#pragma unroll
  for (int rg = 0; rg < 2; ++rg)
#pragma unroll
    for (int kk = 0; kk < 16; ++kk)
      asm volatile("" : "+v"(afr[rg][kk]));

#pragma unroll
  for (int g = 0; g < 4; ++g) {
    f32x16 acc0 = {};
    f32x16 acc1 = {};
#pragma unroll
    for (int kk = 0; kk < 16; ++kk) {
      int row = g * 32 + r5;                 // B col (Z row) this lane holds
      int slot = (kk * 2 + h) ^ r5;          // logical chunk ^ (row&31)
      bf16x8 bf = *(const bf16x8*)&Bs[row * ND + slot * 8];
      acc0 = __builtin_amdgcn_mfma_f32_32x32x16_bf16(afr[0][kk], bf, acc0, 0,
                                                     0, 0);
      acc1 = __builtin_amdgcn_mfma_f32_32x32x16_bf16(afr[1][kk], bf, acc1, 0,
                                                     0, 0);
    }
#pragma unroll
    for (int q = 0; q < 16; ++q) {
      rs[0][q] += exp2f(acc0[q]);
      rs[1][q] += exp2f(acc1[q]);
    }
  }

  // Reduce across the 32 col-lanes (C/D col = lane&31): masks 1..16.
#pragma unroll
  for (int m = 1; m <= 16; m <<= 1)
#pragma unroll
    for (int rg = 0; rg < 2; ++rg)
#pragma unroll
      for (int g = 0; g < 16; ++g)
        rs[rg][g] += __shfl_xor(rs[rg][g], m, 64);

  // C/D row = (reg&3) + 8*(reg>>2) + 4*h (+ rg*32). Writer: r5 == reg.
#pragma unroll
  for (int rg = 0; rg < 2; ++rg)
#pragma unroll
    for (int g = 0; g < 16; ++g)
      if (r5 == g) {
        int rowIn = (g & 3) + 8 * (g >> 2) + 4 * h;
        R[(size_t)(rowA + rg * 32 + rowIn) * 64 + span] = rs[rg][g];
      }
}

// Kernel C: 32 blocks x 256 rows. rowsum[r] = sum_{q<64} R[r][q] - diagE[r];
// term = log(rowsum) - pos[r%B]/T. Block-reduce -> one atomicAdd per block;
// ticketed last block writes out = lossAcc / 2B.
__global__ __launch_bounds__(256) void k_final(
    const float* __restrict__ R, const float* __restrict__ diagE,
    const float* __restrict__ pos, float* __restrict__ lossAcc,
    unsigned int* __restrict__ ticket, float* __restrict__ out) {
  __shared__ float red[4];
  int tid = threadIdx.x;
  int wave = tid >> 6, lane = tid & 63;
  int row = (int)blockIdx.x * 256 + tid;

  const float* Rr = R + (size_t)row * 64;
  float s = -diagE[row];
#pragma unroll
  for (int i = 0; i < 16; ++i) {
    float4 a = *(const float4*)(Rr + i * 4);
    s += (a.x + a.y) + (a.z + a.w);
  }
  float term = __logf(s) - INV_T * pos[row & (NB - 1)];
#pragma unroll
  for (int m = 1; m < 64; m <<= 1) term += __shfl_xor(term, m, 64);
  if (lane == 0) red[wave] = term;
  __syncthreads();
  if (tid == 0) {
    float bs = red[0] + red[1] + red[2] + red[3];
    atomicAdd(lossAcc, bs);
    __threadfence();
    unsigned int old = atomicAdd(ticket, 1u);
    if (old == 31u) {
      float v = atomicAdd(lossAcc, 0.0f);  // atomic read after all adds
      out[0] = v * (1.0f / (float)N2B);
    }
  }
}

extern "C" void kernel_launch(void* const* d_in, const int* in_sizes, int n_in,
                              void* d_out, int out_size, void* d_ws,
                              size_t ws_size, hipStream_t stream) {
  const float* xi = (const float*)d_in[0];
  const float* xj = (const float*)d_in[1];
  float* out = (float*)d_out;
  char* ws = (char*)d_ws;
  unsigned short* Z = (unsigned short*)ws;                  // 4 MiB (B operand)
  unsigned short* Zs = (unsigned short*)(ws + (4u << 20));  // 4 MiB (A, scaled)
  float* R = (float*)(ws + (8u << 20));                     // 8192*64*4 = 2 MiB
  float* pos = (float*)(ws + (10u << 20));                  // 16 KiB
  float* diagE = (float*)(ws + (10u << 20) + 65536);        // 32 KiB
  float* lossAcc = (float*)(ws + (10u << 20) + 131072);
  unsigned int* ticket = (unsigned int*)(ws + (10u << 20) + 131072 + 64);

  k_normalize<<<dim3(NB / 2), dim3(256), 0, stream>>>(xi, xj, Z, Zs, diagE,
                                                      pos, lossAcc, ticket);
  k_gemm_exp<<<dim3(2048), dim3(256), 0, stream>>>(Zs, Z, R);
  k_final<<<dim3(32), dim3(256), 0, stream>>>(R, diagE, pos, lossAcc, ticket,
                                              out);
}

// Round 9
// 108.834 us; speedup vs baseline: 1.2552x; 1.2249x over previous
//
#include <hip/hip_runtime.h>

// Problem constants
#define NB   4096   // B
#define ND   256    // D
#define N2B  8192   // 2B
#define INV_T 2.0f  // 1/TEMP
#define C_EXP 2.8853900817779268f  // 2*log2(e): exp(s*2) == exp2(s*C_EXP)

typedef __attribute__((ext_vector_type(8))) short bf16x8;
typedef __attribute__((ext_vector_type(4))) float f32x4;

__device__ __forceinline__ void gload_lds16(const void* g, void* l) {
  __builtin_amdgcn_global_load_lds(
      (const __attribute__((address_space(1))) void*)g,
      (__attribute__((address_space(3))) void*)l, 16, 0, 0);
}

// fp32 -> bf16 (RNE) as raw bits
__device__ __forceinline__ unsigned short f2b(float f) {
  unsigned int u = __float_as_uint(f);
  u = (u + 0x7fffu + ((u >> 16) & 1u)) >> 16;
  return (unsigned short)u;
}
__device__ __forceinline__ float b2f(unsigned short h) {
  return __uint_as_float(((unsigned int)h) << 16);
}

// Kernel A: L2-normalize rows of [x_i; x_j] -> Z (bf16) and Zs (bf16,
// pre-scaled by C_EXP so the GEMM epilogue is a bare exp2).
//   diagE[zrow] = exp(diag/T)   (self term, subtracted in k_final)
//   pos[r] = dot(z_i[r], z_j[r]) (LDS exchange between i- and j-waves)
// Block 0 zero-inits lossAcc and ticket.
__global__ __launch_bounds__(256) void k_normalize(
    const float* __restrict__ xi, const float* __restrict__ xj,
    unsigned short* __restrict__ Z, unsigned short* __restrict__ Zs,
    float* __restrict__ diagE, float* __restrict__ pos,
    float* __restrict__ lossAcc, unsigned int* __restrict__ ticket) {
  __shared__ float sh[2][256];
  if (blockIdx.x == 0 && threadIdx.x == 0) { *lossAcc = 0.0f; *ticket = 0u; }
  int wave = threadIdx.x >> 6, lane = threadIdx.x & 63;
  int r = (int)blockIdx.x * 2 + (wave & 1);  // row in [0, NB)
  bool isJ = wave >= 2;
  const float* src = (isJ ? xj : xi) + (size_t)r * ND;
  int zrow = r + (isJ ? NB : 0);

  float4 v = *(const float4*)(src + lane * 4);
  float ss = v.x * v.x + v.y * v.y + v.z * v.z + v.w * v.w;
#pragma unroll
  for (int m = 1; m < 64; m <<= 1) ss += __shfl_xor(ss, m, 64);
  float scale = 1.0f / fmaxf(sqrtf(ss), 1e-12f);
  unsigned short h0 = f2b(v.x * scale), h1 = f2b(v.y * scale);
  unsigned short h2 = f2b(v.z * scale), h3 = f2b(v.w * scale);
  ushort4 st; st.x = h0; st.y = h1; st.z = h2; st.w = h3;
  *(ushort4*)(Z + (size_t)zrow * ND + lane * 4) = st;

  float f0 = b2f(h0), f1 = b2f(h1), f2 = b2f(h2), f3 = b2f(h3);
  ushort4 sts;
  sts.x = f2b(f0 * C_EXP); sts.y = f2b(f1 * C_EXP);
  sts.z = f2b(f2 * C_EXP); sts.w = f2b(f3 * C_EXP);
  *(ushort4*)(Zs + (size_t)zrow * ND + lane * 4) = sts;

  float d = f0 * f0 + f1 * f1 + f2 * f2 + f3 * f3;
#pragma unroll
  for (int m = 1; m < 64; m <<= 1) d += __shfl_xor(d, m, 64);
  if (lane == 0) diagE[zrow] = __expf(d * INV_T);

  if (isJ) {
    float* s = sh[wave & 1] + lane * 4;
    s[0] = f0; s[1] = f1; s[2] = f2; s[3] = f3;
  }
  __syncthreads();
  if (!isJ) {
    const float* s = sh[wave] + lane * 4;
    float p = f0 * s[0] + f1 * s[1] + f2 * s[2] + f3 * s[3];
#pragma unroll
    for (int m = 1; m < 64; m <<= 1) p += __shfl_xor(p, m, 64);
    if (lane == 0) pos[r] = p;
  }
}

// Kernel B: R4's register-safe A-stationary band GEMM (the best genuine
// structure) + ping-pong double-buffered staging with fine-grained
// s_waitcnt vmcnt(8) + raw s_barrier (avoids the compiler's vmcnt(0)
// drain before __syncthreads) + exp2 epilogue (A pre-scaled by C_EXP).
// Grid 512 = 64 row-bands (128 rows) x 8 col-spans (1024 cols).
// Each wave holds 32 A-rows in 64 VGPRs (afr[2][8] — FITS, unlike
// R5/R7/R8's 128-reg variants which the compiler silently rematerialized).
// B streams through 2 x 32 KB LDS tiles of 64 cols; batch t+1 stays in
// flight across compute of tile t. Partials -> R[row][8], no atomics.
#define CT 64  // cols per tile
__global__ __launch_bounds__(256, 2) void k_gemm_exp(
    const unsigned short* __restrict__ Zs, const unsigned short* __restrict__ Z,
    float* __restrict__ R) {
  __shared__ alignas(16) unsigned short Bs[2][CT * ND];  // 2 x 32 KiB

  int tid = threadIdx.x;
  int wave = tid >> 6, lane = tid & 63;
  int band = (int)blockIdx.x >> 3;   // 0..63
  int colq = (int)blockIdx.x & 7;    // 0..7
  int quad = lane >> 4, c16 = lane & 15;

  // A fragments (pre-scaled): 2 row-groups of 16, layout A[m=c16][k=kk*32+quad*8+j]
  bf16x8 afr[2][8];
  int rowA = band * 128 + wave * 32;
#pragma unroll
  for (int rg = 0; rg < 2; ++rg)
#pragma unroll
    for (int kk = 0; kk < 8; ++kk)
      afr[rg][kk] = *(const bf16x8*)(Zs + (size_t)(rowA + rg * 16 + c16) * ND +
                                     kk * 32 + quad * 8);

  float rs[2][4];
#pragma unroll
  for (int rg = 0; rg < 2; ++rg)
#pragma unroll
    for (int r = 0; r < 4; ++r) rs[rg][r] = 0.0f;

  int lr1 = lane >> 5;  // row within staging call (0/1)
  int cs = lane & 31;   // LDS chunk slot 0..31

  // Stage tile t (64 Z-rows starting at colq*1024 + t*64) into buffer b.
  // LDS slot s of row zr holds global 16B-chunk (s ^ (zr&31)).
#define STAGE(t, b)                                                       \
  {                                                                       \
    int colbase = colq * 1024 + (t)*CT;                                   \
    _Pragma("unroll") for (int call = 0; call < 8; ++call) {              \
      int r0 = wave * 16 + call * 2;                                      \
      int row = r0 + lr1;                                                 \
      int gc = cs ^ (row & 31);                                           \
      gload_lds16(Z + (size_t)(colbase + row) * ND + gc * 8,              \
                  &Bs[b][r0 * ND]);                                       \
    }                                                                     \
  }

  STAGE(0, 0)
  STAGE(1, 1)

#pragma unroll 2
  for (int t = 0; t < 16; ++t) {
    // Outstanding lds-dma at this point: tiles {t, t+1} = 16 calls.
    // vmcnt(8) -> tile t's 8 calls complete, t+1's stay in flight.
    if (t == 15)
      asm volatile("s_waitcnt vmcnt(0)" ::: "memory");
    else
      asm volatile("s_waitcnt vmcnt(8)" ::: "memory");
    __builtin_amdgcn_s_barrier();

    const unsigned short* Bb = &Bs[t & 1][0];
    f32x4 acc[2][4] = {};
#pragma unroll
    for (int kk = 0; kk < 8; ++kk) {
      bf16x8 bfr[4];
#pragma unroll
      for (int ni = 0; ni < 4; ++ni) {
        int row = ni * 16 + c16;
        int slot = (kk * 4 + quad) ^ (row & 31);
        bfr[ni] = *(const bf16x8*)&Bb[row * ND + slot * 8];
      }
#pragma unroll
      for (int rg = 0; rg < 2; ++rg)
#pragma unroll
        for (int ni = 0; ni < 4; ++ni)
          acc[rg][ni] = __builtin_amdgcn_mfma_f32_16x16x32_bf16(
              afr[rg][kk], bfr[ni], acc[rg][ni], 0, 0, 0);
    }

    // fused exp2 + row-partial accumulate (C/D: col=c16, row=quad*4+reg)
#pragma unroll
    for (int rg = 0; rg < 2; ++rg)
#pragma unroll
      for (int ni = 0; ni < 4; ++ni)
#pragma unroll
        for (int r = 0; r < 4; ++r)
          rs[rg][r] += exp2f(acc[rg][ni][r]);

    // Free buffer (t&1) for tile t+2: own LDS queue drained, then barrier.
    asm volatile("s_waitcnt lgkmcnt(0)" ::: "memory");
    __builtin_amdgcn_s_barrier();
    if (t + 2 < 16) STAGE(t + 2, t & 1)
  }
#undef STAGE

  // reduce row-partials across the 16 cols held per lane group (c16 bits)
#pragma unroll
  for (int m = 1; m <= 8; m <<= 1)
#pragma unroll
    for (int rg = 0; rg < 2; ++rg)
#pragma unroll
      for (int r = 0; r < 4; ++r)
        rs[rg][r] += __shfl_xor(rs[rg][r], m, 64);

#pragma unroll
  for (int rg = 0; rg < 2; ++rg)
#pragma unroll
    for (int r = 0; r < 4; ++r)
      if (c16 == rg * 4 + r) {
        int row = rowA + rg * 16 + quad * 4 + r;
        R[(size_t)row * 8 + colq] = rs[rg][r];
      }
}

// Kernel C: 32 blocks x 256 rows. rowsum[r] = sum_{q<8} R[r][q] - diagE[r];
// term = log(rowsum) - pos[r%B]/T. Block-reduce -> one atomicAdd per block;
// ticketed last block writes out = lossAcc / 2B.
__global__ __launch_bounds__(256) void k_final(
    const float* __restrict__ R, const float* __restrict__ diagE,
    const float* __restrict__ pos, float* __restrict__ lossAcc,
    unsigned int* __restrict__ ticket, float* __restrict__ out) {
  __shared__ float red[4];
  int tid = threadIdx.x;
  int wave = tid >> 6, lane = tid & 63;
  int row = (int)blockIdx.x * 256 + tid;

  const float* Rr = R + (size_t)row * 8;
  float4 a = *(const float4*)(Rr);
  float4 b = *(const float4*)(Rr + 4);
  float s = (a.x + a.y + a.z + a.w) + (b.x + b.y + b.z + b.w) - diagE[row];
  float term = __logf(s) - INV_T * pos[row & (NB - 1)];
#pragma unroll
  for (int m = 1; m < 64; m <<= 1) term += __shfl_xor(term, m, 64);
  if (lane == 0) red[wave] = term;
  __syncthreads();
  if (tid == 0) {
    float bs = red[0] + red[1] + red[2] + red[3];
    atomicAdd(lossAcc, bs);
    __threadfence();
    unsigned int old = atomicAdd(ticket, 1u);
    if (old == 31u) {
      float v = atomicAdd(lossAcc, 0.0f);  // atomic read after all adds
      out[0] = v * (1.0f / (float)N2B);
    }
  }
}

extern "C" void kernel_launch(void* const* d_in, const int* in_sizes, int n_in,
                              void* d_out, int out_size, void* d_ws,
                              size_t ws_size, hipStream_t stream) {
  const float* xi = (const float*)d_in[0];
  const float* xj = (const float*)d_in[1];
  float* out = (float*)d_out;
  char* ws = (char*)d_ws;
  unsigned short* Z = (unsigned short*)ws;                  // 4 MiB (B operand)
  unsigned short* Zs = (unsigned short*)(ws + (4u << 20));  // 4 MiB (A, scaled)
  float* R = (float*)(ws + (8u << 20));                     // 8192*8*4 = 256 KiB
  float* pos = (float*)(ws + (9u << 20));                   // 16 KiB
  float* diagE = (float*)(ws + (9u << 20) + 65536);         // 32 KiB
  float* lossAcc = (float*)(ws + (9u << 20) + 131072);
  unsigned int* ticket = (unsigned int*)(ws + (9u << 20) + 131072 + 64);

  k_normalize<<<dim3(NB / 2), dim3(256), 0, stream>>>(xi, xj, Z, Zs, diagE,
                                                      pos, lossAcc, ticket);
  k_gemm_exp<<<dim3(512), dim3(256), 0, stream>>>(Zs, Z, R);
  k_final<<<dim3(32), dim3(256), 0, stream>>>(R, diagE, pos, lossAcc, ticket,
                                              out);
}